// Round 9
// baseline (495.956 us; speedup 1.0000x reference)
//
#include <hip/hip_runtime.h>
#include <hip/hip_bf16.h>

#define NN 384
#define CC 128
#define HH 60
#define NEL (CC*HH)     // 7680
#define NLAYERS 4

typedef _Float16 f16x4 __attribute__((ext_vector_type(4)));
typedef float f32x4 __attribute__((ext_vector_type(4)));

__device__ __forceinline__ void cvt2(float v, _Float16& hi, _Float16& lo) {
    hi = (_Float16)v; lo = (_Float16)(v - (float)hi);
}

// device-scope grid barrier (all NN blocks co-resident: 256 thr, 2 blocks/CU, 384<=512)
__device__ __forceinline__ void gbar(int* bar, int idx) {
    __syncthreads();
    if (threadIdx.x == 0) {
        __threadfence();                       // release: make prior writes agent-visible
        atomicAdd(&bar[idx], 1);               // device-scope by default
        while (__hip_atomic_load(&bar[idx], __ATOMIC_RELAXED, __HIP_MEMORY_SCOPE_AGENT) < NN)
            __builtin_amdgcn_s_sleep(8);
        __threadfence();                       // acquire: invalidate stale cache state
    }
    __syncthreads();
}

// ============ MFMA core: D[(n*60+h)*256 + r] = sum_k X[h][k] * Wcomb[r][k], f16 x3 split ============
__device__ __forceinline__ void mm_core(char* XhB, char* XlB,
                                        const _Float16* __restrict__ wfhL,
                                        const _Float16* __restrict__ wflL,
                                        float* __restrict__ Dout, int n, int w, int lane)
{
    f16x4 whv[4][8], wlv[4][8];
#pragma unroll
    for (int nt = 0; nt < 4; nt++)
#pragma unroll
        for (int kt = 0; kt < 8; kt++) {
            int idx = (((((w << 2) + nt) << 3) + kt) << 8) + (lane << 2);
            whv[nt][kt] = *(const f16x4*)(wfhL + idx);
            wlv[nt][kt] = *(const f16x4*)(wflL + idx);
        }
    f32x4 acc[4][4];
#pragma unroll
    for (int mt = 0; mt < 4; mt++)
#pragma unroll
        for (int nt = 0; nt < 4; nt++) acc[mt][nt] = (f32x4){0.f, 0.f, 0.f, 0.f};

#pragma unroll
    for (int ks = 0; ks < 8; ks++) {
        f16x4 ah[4], al[4];
#pragma unroll
        for (int mt = 0; mt < 4; mt++) {
            int h = (mt << 4) + (lane & 15);
            int o = (h << 8) + (((ks << 5) + ((lane >> 4) << 3)) ^ ((h & 7) << 4));
            ah[mt] = *(const f16x4*)(XhB + o);
            al[mt] = *(const f16x4*)(XlB + o);
        }
#pragma unroll
        for (int mt = 0; mt < 4; mt++)
#pragma unroll
            for (int nt = 0; nt < 4; nt++) {
                acc[mt][nt] = __builtin_amdgcn_mfma_f32_16x16x16f16(ah[mt], whv[nt][ks], acc[mt][nt], 0, 0, 0);
                acc[mt][nt] = __builtin_amdgcn_mfma_f32_16x16x16f16(al[mt], whv[nt][ks], acc[mt][nt], 0, 0, 0);
                acc[mt][nt] = __builtin_amdgcn_mfma_f32_16x16x16f16(ah[mt], wlv[nt][ks], acc[mt][nt], 0, 0, 0);
            }
    }
    int rb = w << 6;
#pragma unroll
    for (int mt = 0; mt < 4; mt++) {
        int hb = (mt << 4) + ((lane >> 4) << 2);
#pragma unroll
        for (int nt = 0; nt < 4; nt++) {
            int r = rb + (nt << 4) + (lane & 15);
#pragma unroll
            for (int reg = 0; reg < 4; reg++) {
                int h = hb + reg;
                if (h < HH) Dout[(n * HH + h) * 256 + r] = acc[mt][nt][reg];
            }
        }
    }
}

__global__ __launch_bounds__(256, 2) void mega(
    const float* __restrict__ x, const float* __restrict__ ea,
    const float* __restrict__ ew, const float* __restrict__ eb,
    const float* __restrict__ cw, const float* __restrict__ lg,
    const float* __restrict__ lb, const int* __restrict__ ei, int E,
    float* __restrict__ out,
    float* __restrict__ D0, float* __restrict__ D1,
    float* __restrict__ gp, float* __restrict__ bp,
    float* __restrict__ M3, float* __restrict__ v3,
    _Float16* __restrict__ wfh, _Float16* __restrict__ wfl,
    int* __restrict__ off, int* __restrict__ ssrc, int* __restrict__ seid,
    int* __restrict__ bar)
{
    __shared__ __align__(16) char smem[33024];
    const int bid = blockIdx.x, t = threadIdx.x;
    const int w = t >> 6, lane = t & 63;

    // ================= P0: setup =================
    if (bid == 0) {
        int* cnt = (int*)smem;          // NN+1
        int* cur = cnt + NN + 1;        // NN
        for (int i = t; i < NN + 1; i += 256) cnt[i] = 0;
        __syncthreads();
        const int* dstp = ei + E;
        for (int e = t; e < E; e += 256) atomicAdd(&cnt[dstp[e] + 1], 1);
        __syncthreads();
        if (t == 0) { int s = 0; for (int i = 0; i <= NN; i++) { s += cnt[i]; cnt[i] = s; } }
        __syncthreads();
        for (int i = t; i < NN + 1; i += 256) off[i] = cnt[i];
        for (int i = t; i < NN; i += 256) cur[i] = cnt[i];
        __syncthreads();
        for (int e = t; e < E; e += 256) {
            int d = dstp[e];
            int p = atomicAdd(&cur[d], 1);
            ssrc[p] = ei[e];
            seid[p] = e;
        }
    } else if (bid < 5) {
        if (t < CC) {
            int l = bid - 1, c = t;
            const float* wrow = cw + (l * CC + c) * (3 * CC) + 2 * CC;
            const float* ewl = ew + l * CC * 5;
            const float* ebl = eb + l * CC;
            float m0 = 0, m1 = 0, m2 = 0, m3 = 0, m4 = 0, v = 0;
            for (int k = 0; k < CC; k++) {
                float wv = wrow[k];
                const float* e5 = ewl + k * 5;
                m0 = fmaf(wv, e5[0], m0); m1 = fmaf(wv, e5[1], m1); m2 = fmaf(wv, e5[2], m2);
                m3 = fmaf(wv, e5[3], m3); m4 = fmaf(wv, e5[4], m4);
                v  = fmaf(wv, ebl[k], v);
            }
            float* mo = M3 + (l * CC + c) * 5;
            mo[0] = m0; mo[1] = m1; mo[2] = m2; mo[3] = m3; mo[4] = m4;
            v3[l * CC + c] = v;
        }
    } else if (bid < 21) {
        int wid = ((bid - 5) << 2) + w;        // l*16+ng, 0..63
        int l = wid >> 4;
        const float* cwl = cw + l * CC * 3 * CC;
        int r = ((wid & 15) << 4) + (lane & 15);
#pragma unroll
        for (int kt = 0; kt < 8; kt++) {
#pragma unroll
            for (int j = 0; j < 4; j++) {
                int k = (kt << 4) + ((lane >> 4) << 2) + j;
                float wv;
                if (r < 128) wv = cwl[r * 384 + k] - cwl[r * 384 + 128 + k];
                else         wv = cwl[(r - 128) * 384 + 128 + k];
                _Float16 hi, lo; cvt2(wv, hi, lo);
                int idx = (wid * 8 + kt) * 256 + lane * 4 + j;
                wfh[idx] = hi; wfl[idx] = lo;
            }
        }
    } else if (bid < 141) {
        int gidx = ((bid - 21) << 8) + t;      // 0..30719
        int l = gidx / NEL, q = gidx - l * NEL;
        int c = q & 127, h = q >> 7;           // gp layout [l][h*128+c]
        gp[gidx] = lg[l * NEL + c * HH + h];
        bp[gidx] = lb[l * NEL + c * HH + h];
    }
    gbar(bar, 0);

    // ================= P1: layer-0 matmul from canonical x =================
    {
        char* XhB = smem;
        char* XlB = smem + 16384;
        const float* xn = x + bid * NEL;
        for (int p = t; p < 3840; p += 256) {
            int q = p << 1;
            int c = q & 127, h = q >> 7;
            float v0 = xn[c * HH + h], v1 = xn[(c + 1) * HH + h];
            _Float16 h0, l0, h1, l1; cvt2(v0, h0, l0); cvt2(v1, h1, l1);
            int o = (h << 8) + ((c << 1) ^ ((h & 7) << 4));
            union { _Float16 f[2]; unsigned u; } ph, pl;
            ph.f[0] = h0; ph.f[1] = h1; pl.f[0] = l0; pl.f[1] = l1;
            *(unsigned*)(XhB + o) = ph.u;
            *(unsigned*)(XlB + o) = pl.u;
        }
        if (t < 64) {   // zero pad rows 60..63
            int h = 60 + (t >> 4), ch = t & 15;
            int o = (h << 8) + ((ch << 4) ^ ((h & 7) << 4));
            *(uint4*)(XhB + o) = make_uint4(0, 0, 0, 0);
            *(uint4*)(XlB + o) = make_uint4(0, 0, 0, 0);
        }
        __syncthreads();
        mm_core(XhB, XlB, wfh, wfl, D0, bid, w, lane);
    }
    gbar(bar, 1);

    // ================= layers: EDGE(l) [+ MM(l+1) | final store] =================
    const int d = bid;
    const int j0 = off[d], j1 = off[d + 1], cnt = j1 - j0;

    for (int l = 0; l < NLAYERS; l++) {
        const float* Din = (l & 1) ? D1 : D0;
        float* Dnext     = (l & 1) ? D0 : D1;
        const float* M3l = M3 + l * 640;
        const float* v3l = v3 + l * 128;
        const float* gpl = gp + l * NEL;
        const float* bpl = bp + l * NEL;

        float* c3all = (float*)smem;          // 16*128 f32
        float* red   = c3all + 2048;          // 16 f32

        for (int idx = t; idx < (cnt << 7); idx += 256) {
            int j = idx >> 7, c = idx & 127;
            int eid = seid[j0 + j];
            const float* eap = ea + eid * 5;
            const float* m = M3l + c * 5;
            c3all[idx] = v3l[c] + m[0]*eap[0] + m[1]*eap[1] + m[2]*eap[2] + m[3]*eap[3] + m[4]*eap[4];
        }

        float2 areg[15], greg[15], breg[15], accv[15], bv[15], bvn[15];
        const float2* D2 = (const float2*)Din;
        const float2* g2 = (const float2*)gpl;
        const float2* b2 = (const float2*)bpl;
#pragma unroll
        for (int i = 0; i < 15; i++) {
            int p = t + (i << 8);
            areg[i] = D2[(d * HH + (p >> 6)) * 128 + (p & 63)];
            greg[i] = g2[p]; breg[i] = b2[p];
            accv[i] = make_float2(0.f, 0.f);
        }
        {
            int s = ssrc[j0];
#pragma unroll
            for (int i = 0; i < 15; i++) {
                int p = t + (i << 8);
                bv[i] = D2[(s * HH + (p >> 6)) * 128 + 64 + (p & 63)];
            }
        }
        __syncthreads();

        for (int j = 0; j < cnt; j++) {
            if (j + 1 < cnt) {
                int s = ssrc[j0 + j + 1];
#pragma unroll
                for (int i = 0; i < 15; i++) {
                    int p = t + (i << 8);
                    bvn[i] = D2[(s * HH + (p >> 6)) * 128 + 64 + (p & 63)];
                }
            }
            float2 cc = ((const float2*)c3all)[(j << 6) + (t & 63)];
            float sum = 0.f, sq = 0.f;
#pragma unroll
            for (int i = 0; i < 15; i++) {
                float vx = areg[i].x + bv[i].x + cc.x;
                float vy = areg[i].y + bv[i].y + cc.y;
                sum += vx + vy;
                sq = fmaf(vx, vx, fmaf(vy, vy, sq));
            }
#pragma unroll
            for (int o = 32; o; o >>= 1) { sum += __shfl_xor(sum, o); sq += __shfl_xor(sq, o); }
            int jb = j & 1;
            if ((t & 63) == 0) { red[jb * 8 + (t >> 6) * 2] = sum; red[jb * 8 + (t >> 6) * 2 + 1] = sq; }
            asm volatile("s_waitcnt lgkmcnt(0)" ::: "memory");
            __builtin_amdgcn_s_barrier();
            float fs = red[jb*8+0] + red[jb*8+2] + red[jb*8+4] + red[jb*8+6];
            float fq = red[jb*8+1] + red[jb*8+3] + red[jb*8+5] + red[jb*8+7];
            float mu = fs * (1.0f / NEL);
            float var = fq * (1.0f / NEL) - mu * mu;
            float rs = rsqrtf(var + 1e-5f);
#pragma unroll
            for (int i = 0; i < 15; i++) {
                float vx = areg[i].x + bv[i].x + cc.x;
                float vy = areg[i].y + bv[i].y + cc.y;
                float nx = (vx - mu) * rs * greg[i].x + breg[i].x;
                float ny = (vy - mu) * rs * greg[i].y + breg[i].y;
                accv[i].x += fmaxf(nx, 0.f);
                accv[i].y += fmaxf(ny, 0.f);
                bv[i] = bvn[i];
            }
        }

        if (l == NLAYERS - 1) {
#pragma unroll
            for (int i = 0; i < 15; i++) {
                int p = t + (i << 8);
                int h = p >> 6, c = (p & 63) << 1;
                out[d * NEL + c * HH + h] = accv[i].x;
                out[d * NEL + (c + 1) * HH + h] = accv[i].y;
            }
        } else {
            // restage accv (= x_{l+1}[d]) into f16 hi/lo LDS planes, then MFMA layer l+1
            __syncthreads();
            char* XhB = smem;
            char* XlB = smem + 16384;
#pragma unroll
            for (int i = 0; i < 15; i++) {
                int p = t + (i << 8);
                int h = p >> 6;
                int cb = (p & 63) << 2;
                int o = (h << 8) + (cb ^ ((h & 7) << 4));
                _Float16 h0, l0, h1, l1;
                cvt2(accv[i].x, h0, l0); cvt2(accv[i].y, h1, l1);
                union { _Float16 f[2]; unsigned u; } ph, pl;
                ph.f[0] = h0; ph.f[1] = h1; pl.f[0] = l0; pl.f[1] = l1;
                *(unsigned*)(XhB + o) = ph.u;
                *(unsigned*)(XlB + o) = pl.u;
            }
            if (t < 64) {
                int h = 60 + (t >> 4), ch = t & 15;
                int o = (h << 8) + ((ch << 4) ^ ((h & 7) << 4));
                *(uint4*)(XhB + o) = make_uint4(0, 0, 0, 0);
                *(uint4*)(XlB + o) = make_uint4(0, 0, 0, 0);
            }
            __syncthreads();
            mm_core(XhB, XlB, wfh + (l + 1) * 32768, wfl + (l + 1) * 32768, Dnext, d, w, lane);
            gbar(bar, 2 + l);
        }
    }
}

extern "C" void kernel_launch(void* const* d_in, const int* in_sizes, int n_in,
                              void* d_out, int out_size, void* d_ws, size_t ws_size,
                              hipStream_t stream) {
    const float* x  = (const float*)d_in[0];
    const float* ea = (const float*)d_in[1];
    const float* ew = (const float*)d_in[2];
    const float* eb = (const float*)d_in[3];
    const float* cw = (const float*)d_in[4];
    const float* lg = (const float*)d_in[5];
    const float* lb = (const float*)d_in[6];
    const int*   ei = (const int*)d_in[7];
    int E = in_sizes[7] / 2;
    float* out = (float*)d_out;

    float* wsf = (float*)d_ws;
    float* D0 = wsf;                                   // 384*60*256
    float* D1 = D0 + NN * HH * 256;                    // 384*60*256
    float* gp = D1 + NN * HH * 256;                    // 4*7680
    float* bp = gp + NLAYERS * NEL;                    // 4*7680
    float* M3 = bp + NLAYERS * NEL;                    // 4*640
    float* v3 = M3 + NLAYERS * 640;                    // 4*128
    _Float16* wfh = (_Float16*)(v3 + NLAYERS * 128);   // 4*32768
    _Float16* wfl = wfh + NLAYERS * 32768;             // 4*32768
    int* off  = (int*)(wfl + NLAYERS * 32768);         // 385
    int* ssrc = off + (NN + 1);                        // E
    int* seid = ssrc + E;                              // E
    int* bar  = seid + E;                              // 8 counters

    hipMemsetAsync(bar, 0, 8 * sizeof(int), stream);

    mega<<<NN, 256, 0, stream>>>(x, ea, ew, eb, cw, lg, lb, ei, E, out,
                                 D0, D1, gp, bp, M3, v3, wfh, wfl,
                                 off, ssrc, seid, bar);
}

// Round 10
// 352.914 us; speedup vs baseline: 1.4053x; 1.4053x over previous
//
#include <hip/hip_runtime.h>
#include <hip/hip_bf16.h>

#define NN 384
#define CC 128
#define HH 60
#define NEL (CC*HH)     // 7680
#define NLAYERS 4

typedef _Float16 f16x4 __attribute__((ext_vector_type(4)));
typedef float f32x4 __attribute__((ext_vector_type(4)));

__device__ __forceinline__ void cvt2(float v, _Float16& hi, _Float16& lo) {
    hi = (_Float16)v; lo = (_Float16)(v - (float)hi);
}
// XCD-locality swizzle: consecutive node ids (same face/cliques) -> same XCD
__device__ __forceinline__ int nmap(int bid) { return ((bid & 7) * 48) + (bid >> 3); }

// ============ setup: sort (b0), edge-linear fold (b1-4), W frags (b5-20), g/b permute (b21-140) ============
__global__ __launch_bounds__(256) void k_setup(
    const float* __restrict__ cw, const float* __restrict__ ew, const float* __restrict__ eb,
    const float* __restrict__ lg, const float* __restrict__ lb, const int* __restrict__ ei, int E,
    float* __restrict__ M3, float* __restrict__ v3,
    _Float16* __restrict__ wfh, _Float16* __restrict__ wfl,
    float* __restrict__ gp, float* __restrict__ bp,
    int* __restrict__ off, int* __restrict__ ssrc, int* __restrict__ seid)
{
    int bid = blockIdx.x, t = threadIdx.x;
    if (bid == 0) {
        __shared__ int cnt[NN + 1];
        __shared__ int cur[NN];
        for (int i = t; i < NN + 1; i += 256) cnt[i] = 0;
        __syncthreads();
        const int* dstp = ei + E;
        for (int e = t; e < E; e += 256) atomicAdd(&cnt[dstp[e] + 1], 1);
        __syncthreads();
        if (t == 0) { int s = 0; for (int i = 0; i <= NN; i++) { s += cnt[i]; cnt[i] = s; } }
        __syncthreads();
        for (int i = t; i < NN + 1; i += 256) off[i] = cnt[i];
        for (int i = t; i < NN; i += 256) cur[i] = cnt[i];
        __syncthreads();
        for (int e = t; e < E; e += 256) {
            int d = dstp[e];
            int p = atomicAdd(&cur[d], 1);
            ssrc[p] = ei[e];
            seid[p] = e;
        }
    } else if (bid < 5) {
        if (t < CC) {
            int l = bid - 1, c = t;
            const float* wrow = cw + (l * CC + c) * (3 * CC) + 2 * CC;
            const float* ewl = ew + l * CC * 5;
            const float* ebl = eb + l * CC;
            float m0 = 0, m1 = 0, m2 = 0, m3 = 0, m4 = 0, v = 0;
            for (int k = 0; k < CC; k++) {
                float wv = wrow[k];
                const float* e5 = ewl + k * 5;
                m0 = fmaf(wv, e5[0], m0); m1 = fmaf(wv, e5[1], m1); m2 = fmaf(wv, e5[2], m2);
                m3 = fmaf(wv, e5[3], m3); m4 = fmaf(wv, e5[4], m4);
                v  = fmaf(wv, ebl[k], v);
            }
            float* mo = M3 + (l * CC + c) * 5;
            mo[0] = m0; mo[1] = m1; mo[2] = m2; mo[3] = m3; mo[4] = m4;
            v3[l * CC + c] = v;
        }
    } else if (bid < 21) {
        int wid = ((bid - 5) << 2) + (t >> 6);   // l*16+ng
        int lane = t & 63;
        int l = wid >> 4;
        const float* cwl = cw + l * CC * 3 * CC;
        int r = ((wid & 15) << 4) + (lane & 15);
#pragma unroll
        for (int kt = 0; kt < 8; kt++) {
#pragma unroll
            for (int j = 0; j < 4; j++) {
                int k = (kt << 4) + ((lane >> 4) << 2) + j;
                float wv;
                if (r < 128) wv = cwl[r * 384 + k] - cwl[r * 384 + 128 + k];
                else         wv = cwl[(r - 128) * 384 + 128 + k];
                _Float16 hi, lo; cvt2(wv, hi, lo);
                int idx = (wid * 8 + kt) * 256 + lane * 4 + j;
                wfh[idx] = hi; wfl[idx] = lo;
            }
        }
    } else if (bid < 141) {
        int gidx = ((bid - 21) << 8) + t;       // 0..30719
        int l = gidx / NEL, q = gidx - l * NEL;
        int c = q & 127, h = q >> 7;            // gp layout [l][h*128+c]
        gp[gidx] = lg[l * NEL + c * HH + h];
        bp[gidx] = lb[l * NEL + c * HH + h];
    }
}

// ============ MFMA core -> separate A (r<128) and B (r>=128) arrays, node stride 7680 ============
__device__ __forceinline__ void mm_core(char* XhB, char* XlB,
                                        const _Float16* __restrict__ wfhL,
                                        const _Float16* __restrict__ wflL,
                                        float* __restrict__ Aout, float* __restrict__ Bout,
                                        int n, int w, int lane)
{
    f16x4 whv[4][8];
#pragma unroll
    for (int nt = 0; nt < 4; nt++)
#pragma unroll
        for (int kt = 0; kt < 8; kt++)
            whv[nt][kt] = *(const f16x4*)(wfhL + (((((w << 2) + nt) << 3) + kt) << 8) + (lane << 2));

    f32x4 acc[4][4];
#pragma unroll
    for (int mt = 0; mt < 4; mt++)
#pragma unroll
        for (int nt = 0; nt < 4; nt++) acc[mt][nt] = (f32x4){0.f, 0.f, 0.f, 0.f};

#pragma unroll
    for (int ks = 0; ks < 8; ks++) {
        f16x4 wlv[4];
#pragma unroll
        for (int nt = 0; nt < 4; nt++)
            wlv[nt] = *(const f16x4*)(wflL + (((((w << 2) + nt) << 3) + ks) << 8) + (lane << 2));
        f16x4 ah[4], al[4];
#pragma unroll
        for (int mt = 0; mt < 4; mt++) {
            int h = (mt << 4) + (lane & 15);
            int o = (h << 8) + (((ks << 5) + ((lane >> 4) << 3)) ^ ((h & 7) << 4));
            ah[mt] = *(const f16x4*)(XhB + o);
            al[mt] = *(const f16x4*)(XlB + o);
        }
#pragma unroll
        for (int mt = 0; mt < 4; mt++)
#pragma unroll
            for (int nt = 0; nt < 4; nt++) {
                acc[mt][nt] = __builtin_amdgcn_mfma_f32_16x16x16f16(ah[mt], whv[nt][ks], acc[mt][nt], 0, 0, 0);
                acc[mt][nt] = __builtin_amdgcn_mfma_f32_16x16x16f16(al[mt], whv[nt][ks], acc[mt][nt], 0, 0, 0);
                acc[mt][nt] = __builtin_amdgcn_mfma_f32_16x16x16f16(ah[mt], wlv[nt], acc[mt][nt], 0, 0, 0);
            }
    }
    // w<2 -> A cols [w*64..), w>=2 -> B cols [(w-2)*64..)
    float* Out = ((w < 2) ? Aout : Bout) + n * NEL + ((w & 1) << 6);
#pragma unroll
    for (int mt = 0; mt < 4; mt++) {
        int hb = (mt << 4) + ((lane >> 4) << 2);
#pragma unroll
        for (int nt = 0; nt < 4; nt++) {
            int rl = (nt << 4) + (lane & 15);
#pragma unroll
            for (int reg = 0; reg < 4; reg++) {
                int h = hb + reg;
                if (h < HH) Out[h * 128 + rl] = acc[mt][nt][reg];
            }
        }
    }
}

// ============ layer-0 matmul from canonical x ============
__global__ __launch_bounds__(256, 3) void k_mm0(const float* __restrict__ x,
                                                const _Float16* __restrict__ wfhL,
                                                const _Float16* __restrict__ wflL,
                                                float* __restrict__ Aout, float* __restrict__ Bout)
{
    __shared__ __align__(16) char smem[33024];
    char* XhB = smem;
    char* XlB = smem + 16384;
    int n = nmap(blockIdx.x), t = threadIdx.x;
    int w = t >> 6, lane = t & 63;

    const float* xn = x + n * NEL;
    for (int p = t; p < 3840; p += 256) {
        int q = p << 1;
        int c = q & 127, h = q >> 7;
        float v0 = xn[c * HH + h], v1 = xn[(c + 1) * HH + h];
        _Float16 h0, l0, h1, l1; cvt2(v0, h0, l0); cvt2(v1, h1, l1);
        int o = (h << 8) + ((c << 1) ^ ((h & 7) << 4));
        union { _Float16 f[2]; unsigned u; } ph, pl;
        ph.f[0] = h0; ph.f[1] = h1; pl.f[0] = l0; pl.f[1] = l1;
        *(unsigned*)(XhB + o) = ph.u;
        *(unsigned*)(XlB + o) = pl.u;
    }
    if (t < 64) {   // zero pad rows 60..63
        int h = 60 + (t >> 4), ch = t & 15;
        int o = (h << 8) + ((ch << 4) ^ ((h & 7) << 4));
        *(uint4*)(XhB + o) = make_uint4(0, 0, 0, 0);
        *(uint4*)(XlB + o) = make_uint4(0, 0, 0, 0);
    }
    __syncthreads();
    mm_core(XhB, XlB, wfhL, wflL, Aout, Bout, n, w, lane);
}

// ============ fused: EDGE(layer l) [+ MM(layer l+1) | final store] ============
template<bool LAST>
__global__ __launch_bounds__(256, 3) void k_fused(
    const float* __restrict__ Ain, const float* __restrict__ Bin,
    const float* __restrict__ ea,
    const float* __restrict__ M3l, const float* __restrict__ v3l,
    const float* __restrict__ gpl, const float* __restrict__ bpl,
    const int* __restrict__ off, const int* __restrict__ ssrc, const int* __restrict__ seid,
    const _Float16* __restrict__ wfhL, const _Float16* __restrict__ wflL,
    float* __restrict__ Aout, float* __restrict__ Bout)
{
    __shared__ __align__(16) char smem[33024];
    int d = nmap(blockIdx.x), t = threadIdx.x;
    int w = t >> 6, lane = t & 63;
    float* c3all = (float*)smem;          // 16*128 f32
    float* red   = c3all + 2048;          // 16 f32

    int j0 = off[d], j1 = off[d + 1], cnt = j1 - j0;

    for (int idx = t; idx < (cnt << 7); idx += 256) {
        int j = idx >> 7, c = idx & 127;
        int eid = seid[j0 + j];
        const float* eap = ea + eid * 5;
        const float* m = M3l + c * 5;
        c3all[idx] = v3l[c] + m[0]*eap[0] + m[1]*eap[1] + m[2]*eap[2] + m[3]*eap[3] + m[4]*eap[4];
    }

    float2 areg[15], greg[15], breg[15], accv[15], bv[15], bvn[15];
    const float2* A2 = (const float2*)(Ain + d * NEL);
    const float2* g2 = (const float2*)gpl;
    const float2* b2 = (const float2*)bpl;
#pragma unroll
    for (int i = 0; i < 15; i++) {
        int p = t + (i << 8);
        areg[i] = A2[p]; greg[i] = g2[p]; breg[i] = b2[p];
        accv[i] = make_float2(0.f, 0.f);
    }
    {
        const float2* B2 = (const float2*)(Bin + ssrc[j0] * NEL);
#pragma unroll
        for (int i = 0; i < 15; i++) bv[i] = B2[t + (i << 8)];
    }
    __syncthreads();

    for (int j = 0; j < cnt; j++) {
        if (j + 1 < cnt) {
            const float2* B2 = (const float2*)(Bin + ssrc[j0 + j + 1] * NEL);
#pragma unroll
            for (int i = 0; i < 15; i++) bvn[i] = B2[t + (i << 8)];
        }
        float2 cc = ((const float2*)c3all)[(j << 6) + (t & 63)];
        float sum = 0.f, sq = 0.f;
#pragma unroll
        for (int i = 0; i < 15; i++) {
            float vx = areg[i].x + bv[i].x + cc.x;
            float vy = areg[i].y + bv[i].y + cc.y;
            sum += vx + vy;
            sq = fmaf(vx, vx, fmaf(vy, vy, sq));
        }
#pragma unroll
        for (int o = 32; o; o >>= 1) { sum += __shfl_xor(sum, o); sq += __shfl_xor(sq, o); }
        int jb = j & 1;
        if ((t & 63) == 0) { red[jb * 8 + (t >> 6) * 2] = sum; red[jb * 8 + (t >> 6) * 2 + 1] = sq; }
        asm volatile("s_waitcnt lgkmcnt(0)" ::: "memory");
        __builtin_amdgcn_s_barrier();
        float fs = red[jb*8+0] + red[jb*8+2] + red[jb*8+4] + red[jb*8+6];
        float fq = red[jb*8+1] + red[jb*8+3] + red[jb*8+5] + red[jb*8+7];
        float mu = fs * (1.0f / NEL);
        float var = fq * (1.0f / NEL) - mu * mu;
        float rs = rsqrtf(var + 1e-5f);
#pragma unroll
        for (int i = 0; i < 15; i++) {
            float vx = areg[i].x + bv[i].x + cc.x;
            float vy = areg[i].y + bv[i].y + cc.y;
            float nx = (vx - mu) * rs * greg[i].x + breg[i].x;
            float ny = (vy - mu) * rs * greg[i].y + breg[i].y;
            accv[i].x += fmaxf(nx, 0.f);
            accv[i].y += fmaxf(ny, 0.f);
            bv[i] = bvn[i];
        }
    }

    if (LAST) {
#pragma unroll
        for (int i = 0; i < 15; i++) {
            int p = t + (i << 8);
            int h = p >> 6, c = (p & 63) << 1;
            Aout[d * NEL + c * HH + h] = accv[i].x;
            Aout[d * NEL + (c + 1) * HH + h] = accv[i].y;
        }
    } else {
        // restage accv (= x_{l+1}[d]) into f16 hi/lo LDS planes, then MFMA layer l+1
        __syncthreads();
        char* XhB = smem;
        char* XlB = smem + 16384;
#pragma unroll
        for (int i = 0; i < 15; i++) {
            int p = t + (i << 8);
            int h = p >> 6;
            int cb = (p & 63) << 2;
            int o = (h << 8) + (cb ^ ((h & 7) << 4));
            _Float16 h0, l0, h1, l1;
            cvt2(accv[i].x, h0, l0); cvt2(accv[i].y, h1, l1);
            union { _Float16 f[2]; unsigned u; } ph, pl;
            ph.f[0] = h0; ph.f[1] = h1; pl.f[0] = l0; pl.f[1] = l1;
            *(unsigned*)(XhB + o) = ph.u;
            *(unsigned*)(XlB + o) = pl.u;
        }
        if (t < 64) {
            int h = 60 + (t >> 4), ch = t & 15;
            int o = (h << 8) + ((ch << 4) ^ ((h & 7) << 4));
            *(uint4*)(XhB + o) = make_uint4(0, 0, 0, 0);
            *(uint4*)(XlB + o) = make_uint4(0, 0, 0, 0);
        }
        __syncthreads();
        mm_core(XhB, XlB, wfhL, wflL, Aout, Bout, d, w, lane);
    }
}

extern "C" void kernel_launch(void* const* d_in, const int* in_sizes, int n_in,
                              void* d_out, int out_size, void* d_ws, size_t ws_size,
                              hipStream_t stream) {
    const float* x  = (const float*)d_in[0];
    const float* ea = (const float*)d_in[1];
    const float* ew = (const float*)d_in[2];
    const float* eb = (const float*)d_in[3];
    const float* cw = (const float*)d_in[4];
    const float* lg = (const float*)d_in[5];
    const float* lb = (const float*)d_in[6];
    const int*   ei = (const int*)d_in[7];
    int E = in_sizes[7] / 2;
    float* out = (float*)d_out;

    float* wsf = (float*)d_ws;
    float* A0 = wsf;                                   // 384*7680
    float* B0 = A0 + NN * NEL;
    float* A1 = B0 + NN * NEL;
    float* B1 = A1 + NN * NEL;
    float* gp = B1 + NN * NEL;                         // 4*7680
    float* bp = gp + NLAYERS * NEL;                    // 4*7680
    float* M3 = bp + NLAYERS * NEL;                    // 4*640
    float* v3 = M3 + NLAYERS * 640;                    // 4*128
    _Float16* wfh = (_Float16*)(v3 + NLAYERS * 128);   // 4*32768
    _Float16* wfl = wfh + NLAYERS * 32768;             // 4*32768
    int* off  = (int*)(wfl + NLAYERS * 32768);         // 385
    int* ssrc = off + (NN + 1);                        // E
    int* seid = ssrc + E;                              // E

    k_setup<<<141, 256, 0, stream>>>(cw, ew, eb, lg, lb, ei, E,
                                     M3, v3, wfh, wfl, gp, bp, off, ssrc, seid);
    k_mm0<<<NN, 256, 0, stream>>>(x, wfh, wfl, A0, B0);

    k_fused<false><<<NN, 256, 0, stream>>>(A0, B0, ea, M3 + 0 * 640, v3 + 0 * 128,
                                           gp + 0 * NEL, bp + 0 * NEL, off, ssrc, seid,
                                           wfh + 1 * 32768, wfl + 1 * 32768, A1, B1);
    k_fused<false><<<NN, 256, 0, stream>>>(A1, B1, ea, M3 + 1 * 640, v3 + 1 * 128,
                                           gp + 1 * NEL, bp + 1 * NEL, off, ssrc, seid,
                                           wfh + 2 * 32768, wfl + 2 * 32768, A0, B0);
    k_fused<false><<<NN, 256, 0, stream>>>(A0, B0, ea, M3 + 2 * 640, v3 + 2 * 128,
                                           gp + 2 * NEL, bp + 2 * NEL, off, ssrc, seid,
                                           wfh + 3 * 32768, wfl + 3 * 32768, A1, B1);
    k_fused<true><<<NN, 256, 0, stream>>>(A1, B1, ea, M3 + 3 * 640, v3 + 3 * 128,
                                          gp + 3 * NEL, bp + 3 * NEL, off, ssrc, seid,
                                          wfh, wfl, out, out);
}

// Round 11
// 199.833 us; speedup vs baseline: 2.4819x; 1.7660x over previous
//
#include <hip/hip_runtime.h>
#include <hip/hip_bf16.h>

#define NN 384
#define CC 128
#define HH 60
#define NEL (CC*HH)     // 7680
#define NLAYERS 4

typedef _Float16 f16x4 __attribute__((ext_vector_type(4)));
typedef float f32x4 __attribute__((ext_vector_type(4)));

__device__ __forceinline__ void cvt2(float v, _Float16& hi, _Float16& lo) {
    hi = (_Float16)v; lo = (_Float16)(v - (float)hi);
}
// XCD-locality swizzle: consecutive node ids (same face/cliques) -> same XCD
__device__ __forceinline__ int nmap(int bid) { return ((bid & 7) * 48) + (bid >> 3); }

// ============ setup: sort (b0), edge-linear fold (b1-4), W frags (b5-20), g/b permute (b21-140) ============
__global__ __launch_bounds__(256) void k_setup(
    const float* __restrict__ cw, const float* __restrict__ ew, const float* __restrict__ eb,
    const float* __restrict__ lg, const float* __restrict__ lb, const int* __restrict__ ei, int E,
    float* __restrict__ M3, float* __restrict__ v3,
    _Float16* __restrict__ wfh, _Float16* __restrict__ wfl,
    float* __restrict__ gp, float* __restrict__ bp,
    int* __restrict__ off, int* __restrict__ ssrc, int* __restrict__ seid)
{
    int bid = blockIdx.x, t = threadIdx.x;
    if (bid == 0) {
        __shared__ int cnt[NN + 1];
        __shared__ int cur[NN];
        for (int i = t; i < NN + 1; i += 256) cnt[i] = 0;
        __syncthreads();
        const int* dstp = ei + E;
        for (int e = t; e < E; e += 256) atomicAdd(&cnt[dstp[e] + 1], 1);
        __syncthreads();
        if (t == 0) { int s = 0; for (int i = 0; i <= NN; i++) { s += cnt[i]; cnt[i] = s; } }
        __syncthreads();
        for (int i = t; i < NN + 1; i += 256) off[i] = cnt[i];
        for (int i = t; i < NN; i += 256) cur[i] = cnt[i];
        __syncthreads();
        for (int e = t; e < E; e += 256) {
            int d = dstp[e];
            int p = atomicAdd(&cur[d], 1);
            ssrc[p] = ei[e];
            seid[p] = e;
        }
    } else if (bid < 5) {
        if (t < CC) {
            int l = bid - 1, c = t;
            const float* wrow = cw + (l * CC + c) * (3 * CC) + 2 * CC;
            const float* ewl = ew + l * CC * 5;
            const float* ebl = eb + l * CC;
            float m0 = 0, m1 = 0, m2 = 0, m3 = 0, m4 = 0, v = 0;
            for (int k = 0; k < CC; k++) {
                float wv = wrow[k];
                const float* e5 = ewl + k * 5;
                m0 = fmaf(wv, e5[0], m0); m1 = fmaf(wv, e5[1], m1); m2 = fmaf(wv, e5[2], m2);
                m3 = fmaf(wv, e5[3], m3); m4 = fmaf(wv, e5[4], m4);
                v  = fmaf(wv, ebl[k], v);
            }
            float* mo = M3 + (l * CC + c) * 5;
            mo[0] = m0; mo[1] = m1; mo[2] = m2; mo[3] = m3; mo[4] = m4;
            v3[l * CC + c] = v;
        }
    } else if (bid < 21) {
        int wid = ((bid - 5) << 2) + (t >> 6);   // l*16+ng
        int lane = t & 63;
        int l = wid >> 4;
        const float* cwl = cw + l * CC * 3 * CC;
        int r = ((wid & 15) << 4) + (lane & 15);
#pragma unroll
        for (int kt = 0; kt < 8; kt++) {
#pragma unroll
            for (int j = 0; j < 4; j++) {
                int k = (kt << 4) + ((lane >> 4) << 2) + j;
                float wv;
                if (r < 128) wv = cwl[r * 384 + k] - cwl[r * 384 + 128 + k];
                else         wv = cwl[(r - 128) * 384 + 128 + k];
                _Float16 hi, lo; cvt2(wv, hi, lo);
                int idx = (wid * 8 + kt) * 256 + lane * 4 + j;
                wfh[idx] = hi; wfl[idx] = lo;
            }
        }
    } else if (bid < 141) {
        int gidx = ((bid - 21) << 8) + t;       // 0..30719
        int l = gidx / NEL, q = gidx - l * NEL;
        int c = q & 127, h = q >> 7;            // gp layout [l][h*128+c]
        gp[gidx] = lg[l * NEL + c * HH + h];
        bp[gidx] = lb[l * NEL + c * HH + h];
    }
}

// ============ 8-wave MFMA core: wave w covers 32 output cols; whv upfront, wlv streamed ============
__device__ __forceinline__ void mm_core8(char* XhB, char* XlB,
                                         const _Float16* __restrict__ wfhL,
                                         const _Float16* __restrict__ wflL,
                                         float* __restrict__ Aout, float* __restrict__ Bout,
                                         int n, int w, int lane)
{
    f16x4 whv[2][8];
#pragma unroll
    for (int nt = 0; nt < 2; nt++)
#pragma unroll
        for (int kt = 0; kt < 8; kt++)
            whv[nt][kt] = *(const f16x4*)(wfhL + (((((w << 1) + nt) << 3) + kt) << 8) + (lane << 2));

    f32x4 acc[4][2];
#pragma unroll
    for (int mt = 0; mt < 4; mt++)
#pragma unroll
        for (int nt = 0; nt < 2; nt++) acc[mt][nt] = (f32x4){0.f, 0.f, 0.f, 0.f};

#pragma unroll
    for (int ks = 0; ks < 8; ks++) {
        f16x4 wlv[2];
#pragma unroll
        for (int nt = 0; nt < 2; nt++)
            wlv[nt] = *(const f16x4*)(wflL + (((((w << 1) + nt) << 3) + ks) << 8) + (lane << 2));
        f16x4 ah[4], al[4];
#pragma unroll
        for (int mt = 0; mt < 4; mt++) {
            int h = (mt << 4) + (lane & 15);
            int o = (h << 8) + (((ks << 5) + ((lane >> 4) << 3)) ^ ((h & 7) << 4));
            ah[mt] = *(const f16x4*)(XhB + o);
            al[mt] = *(const f16x4*)(XlB + o);
        }
#pragma unroll
        for (int mt = 0; mt < 4; mt++)
#pragma unroll
            for (int nt = 0; nt < 2; nt++) {
                acc[mt][nt] = __builtin_amdgcn_mfma_f32_16x16x16f16(ah[mt], whv[nt][ks], acc[mt][nt], 0, 0, 0);
                acc[mt][nt] = __builtin_amdgcn_mfma_f32_16x16x16f16(al[mt], whv[nt][ks], acc[mt][nt], 0, 0, 0);
                acc[mt][nt] = __builtin_amdgcn_mfma_f32_16x16x16f16(ah[mt], wlv[nt], acc[mt][nt], 0, 0, 0);
            }
    }
    // w<4 -> A cols [(w&3)*32..), w>=4 -> B cols
    float* Out = ((w < 4) ? Aout : Bout) + n * NEL + ((w & 3) << 5);
#pragma unroll
    for (int mt = 0; mt < 4; mt++) {
        int hb = (mt << 4) + ((lane >> 4) << 2);
#pragma unroll
        for (int nt = 0; nt < 2; nt++) {
            int rl = (nt << 4) + (lane & 15);
#pragma unroll
            for (int reg = 0; reg < 4; reg++) {
                int h = hb + reg;
                if (h < HH) Out[h * 128 + rl] = acc[mt][nt][reg];
            }
        }
    }
}

// ============ layer-0 matmul from canonical x, 512 threads ============
__global__ __launch_bounds__(512, 4) void k_mm0(const float* __restrict__ x,
                                                const _Float16* __restrict__ wfhL,
                                                const _Float16* __restrict__ wflL,
                                                float* __restrict__ Aout, float* __restrict__ Bout)
{
    __shared__ __align__(16) char smem[32768];
    char* XhB = smem;
    char* XlB = smem + 16384;
    int n = nmap(blockIdx.x), t = threadIdx.x;
    int w = t >> 6, lane = t & 63;

    const float* xn = x + n * NEL;
    for (int p = t; p < 3840; p += 512) {
        int q = p << 1;
        int c = q & 127, h = q >> 7;
        float v0 = xn[c * HH + h], v1 = xn[(c + 1) * HH + h];
        _Float16 h0, l0, h1, l1; cvt2(v0, h0, l0); cvt2(v1, h1, l1);
        int o = (h << 8) + ((c << 1) ^ ((h & 7) << 4));
        union { _Float16 f[2]; unsigned u; } ph, pl;
        ph.f[0] = h0; ph.f[1] = h1; pl.f[0] = l0; pl.f[1] = l1;
        *(unsigned*)(XhB + o) = ph.u;
        *(unsigned*)(XlB + o) = pl.u;
    }
    if (t < 64) {   // zero pad rows 60..63
        int h = 60 + (t >> 4), ch = t & 15;
        int o = (h << 8) + ((ch << 4) ^ ((h & 7) << 4));
        *(uint4*)(XhB + o) = make_uint4(0, 0, 0, 0);
        *(uint4*)(XlB + o) = make_uint4(0, 0, 0, 0);
    }
    __syncthreads();
    mm_core8(XhB, XlB, wfhL, wflL, Aout, Bout, n, w, lane);
}

// ============ fused: EDGE(layer l) [+ MM(layer l+1) | final store], 512 threads ============
template<bool LAST>
__global__ __launch_bounds__(512, 4) void k_fused(
    const float* __restrict__ Ain, const float* __restrict__ Bin,
    const float* __restrict__ ea,
    const float* __restrict__ M3l, const float* __restrict__ v3l,
    const float* __restrict__ gpl, const float* __restrict__ bpl,
    const int* __restrict__ off, const int* __restrict__ ssrc, const int* __restrict__ seid,
    const _Float16* __restrict__ wfhL, const _Float16* __restrict__ wflL,
    float* __restrict__ Aout, float* __restrict__ Bout)
{
    __shared__ __align__(16) char smem[32768];
    int d = nmap(blockIdx.x), t = threadIdx.x;
    int w = t >> 6, lane = t & 63;
    float* c3all = (float*)smem;          // 8*128 f32
    float* red   = c3all + 1024;          // 2*16 f32

    int j0 = off[d], j1 = off[d + 1], cnt = j1 - j0;   // cnt == 8

    for (int idx = t; idx < (cnt << 7); idx += 512) {
        int j = idx >> 7, c = idx & 127;
        int eid = seid[j0 + j];
        const float* eap = ea + eid * 5;
        const float* m = M3l + c * 5;
        c3all[idx] = v3l[c] + m[0]*eap[0] + m[1]*eap[1] + m[2]*eap[2] + m[3]*eap[3] + m[4]*eap[4];
    }

    // p = t + i*512 -> channel c = t&127 constant across i; h = (t>>7) + 4*i
    float areg[15], greg[15], breg[15], accv[15];
    const float* Ad = Ain + d * NEL;
#pragma unroll
    for (int i = 0; i < 15; i++) {
        int p = t + (i << 9);
        areg[i] = Ad[p]; greg[i] = gpl[p]; breg[i] = bpl[p];
        accv[i] = 0.f;
    }
    const int cch = t & 127;
    __syncthreads();

    for (int j = 0; j < cnt; j++) {
        const float* Bs = Bin + ssrc[j0 + j] * NEL;
        float cc = c3all[(j << 7) + cch];
        float bv[15];
        float sum = 0.f, sq = 0.f;
#pragma unroll
        for (int i = 0; i < 15; i++) {
            float v = areg[i] + Bs[t + (i << 9)] + cc;
            bv[i] = v;
            sum += v;
            sq = fmaf(v, v, sq);
        }
#pragma unroll
        for (int o = 32; o; o >>= 1) { sum += __shfl_xor(sum, o); sq += __shfl_xor(sq, o); }
        int jb = j & 1;
        if (lane == 0) { red[jb * 16 + w * 2] = sum; red[jb * 16 + w * 2 + 1] = sq; }
        __syncthreads();
        float fs = 0.f, fq = 0.f;
#pragma unroll
        for (int k = 0; k < 8; k++) { fs += red[jb * 16 + k * 2]; fq += red[jb * 16 + k * 2 + 1]; }
        float mu = fs * (1.0f / NEL);
        float var = fq * (1.0f / NEL) - mu * mu;
        float rs = rsqrtf(var + 1e-5f);
#pragma unroll
        for (int i = 0; i < 15; i++) {
            float nx = (bv[i] - mu) * rs * greg[i] + breg[i];
            accv[i] += fmaxf(nx, 0.f);
        }
    }

    if (LAST) {
        // LDS transpose [c][h] padded 61 -> coalesced out writes
        __syncthreads();
        float* xt = (float*)smem;     // 128*61 f32 = 31232 B
        int hb0 = t >> 7;
#pragma unroll
        for (int i = 0; i < 15; i++)
            xt[cch * 61 + hb0 + (i << 2)] = accv[i];
        __syncthreads();
        for (int o2 = t; o2 < NEL; o2 += 512) {
            int c2 = o2 / 60, h2 = o2 - c2 * 60;
            Aout[d * NEL + o2] = xt[c2 * 61 + h2];
        }
    } else {
        // restage accv (= x_{l+1}[d]) into f16 hi/lo LDS planes, then MFMA layer l+1
        __syncthreads();
        char* XhB = smem;
        char* XlB = smem + 16384;
        int hb0 = t >> 7;
#pragma unroll
        for (int i = 0; i < 15; i++) {
            int h = hb0 + (i << 2);
            int o = (h << 8) + ((cch << 1) ^ ((h & 7) << 4));
            _Float16 hi, lo; cvt2(accv[i], hi, lo);
            *(_Float16*)(XhB + o) = hi;
            *(_Float16*)(XlB + o) = lo;
        }
        if (t < 64) {
            int h = 60 + (t >> 4), ch = t & 15;
            int o = (h << 8) + ((ch << 4) ^ ((h & 7) << 4));
            *(uint4*)(XhB + o) = make_uint4(0, 0, 0, 0);
            *(uint4*)(XlB + o) = make_uint4(0, 0, 0, 0);
        }
        __syncthreads();
        mm_core8(XhB, XlB, wfhL, wflL, Aout, Bout, d, w, lane);
    }
}

extern "C" void kernel_launch(void* const* d_in, const int* in_sizes, int n_in,
                              void* d_out, int out_size, void* d_ws, size_t ws_size,
                              hipStream_t stream) {
    const float* x  = (const float*)d_in[0];
    const float* ea = (const float*)d_in[1];
    const float* ew = (const float*)d_in[2];
    const float* eb = (const float*)d_in[3];
    const float* cw = (const float*)d_in[4];
    const float* lg = (const float*)d_in[5];
    const float* lb = (const float*)d_in[6];
    const int*   ei = (const int*)d_in[7];
    int E = in_sizes[7] / 2;
    float* out = (float*)d_out;

    float* wsf = (float*)d_ws;
    float* A0 = wsf;                                   // 384*7680
    float* B0 = A0 + NN * NEL;
    float* A1 = B0 + NN * NEL;
    float* B1 = A1 + NN * NEL;
    float* gp = B1 + NN * NEL;                         // 4*7680
    float* bp = gp + NLAYERS * NEL;                    // 4*7680
    float* M3 = bp + NLAYERS * NEL;                    // 4*640
    float* v3 = M3 + NLAYERS * 640;                    // 4*128
    _Float16* wfh = (_Float16*)(v3 + NLAYERS * 128);   // 4*32768
    _Float16* wfl = wfh + NLAYERS * 32768;             // 4*32768
    int* off  = (int*)(wfl + NLAYERS * 32768);         // 385
    int* ssrc = off + (NN + 1);                        // E
    int* seid = ssrc + E;                              // E

    k_setup<<<141, 256, 0, stream>>>(cw, ew, eb, lg, lb, ei, E,
                                     M3, v3, wfh, wfl, gp, bp, off, ssrc, seid);
    k_mm0<<<NN, 512, 0, stream>>>(x, wfh, wfl, A0, B0);

    k_fused<false><<<NN, 512, 0, stream>>>(A0, B0, ea, M3 + 0 * 640, v3 + 0 * 128,
                                           gp + 0 * NEL, bp + 0 * NEL, off, ssrc, seid,
                                           wfh + 1 * 32768, wfl + 1 * 32768, A1, B1);
    k_fused<false><<<NN, 512, 0, stream>>>(A1, B1, ea, M3 + 1 * 640, v3 + 1 * 128,
                                           gp + 1 * NEL, bp + 1 * NEL, off, ssrc, seid,
                                           wfh + 2 * 32768, wfl + 2 * 32768, A0, B0);
    k_fused<false><<<NN, 512, 0, stream>>>(A0, B0, ea, M3 + 2 * 640, v3 + 2 * 128,
                                           gp + 2 * NEL, bp + 2 * NEL, off, ssrc, seid,
                                           wfh + 3 * 32768, wfl + 3 * 32768, A1, B1);
    k_fused<true><<<NN, 512, 0, stream>>>(A1, B1, ea, M3 + 3 * 640, v3 + 3 * 128,
                                          gp + 3 * NEL, bp + 3 * NEL, off, ssrc, seid,
                                          wfh, wfl, out, out);
}